// Round 5
// baseline (248.948 us; speedup 1.0000x reference)
//
#include <hip/hip_runtime.h>
#include <hip/hip_bf16.h>

typedef __attribute__((ext_vector_type(8))) short short8;
typedef __attribute__((ext_vector_type(4))) float f32x4;

__device__ __forceinline__ unsigned short f2bf(float f){
    unsigned u = __float_as_uint(f);
    unsigned r = (u + 0x7FFFu + ((u >> 16) & 1u)) >> 16;
    return (unsigned short)r;
}

// swizzled LDS byte offset for row-major bf16 tiles (stride 256B or 512B)
__device__ __forceinline__ unsigned swz(unsigned row, unsigned byte_in_row, unsigned stride){
    return (row * stride + byte_in_row) ^ ((row & 7u) << 4);
}

// ---- prep: transpose + bf16-convert weights ----
// W1T [256][128], W2T [128][256], W3T [512][256]  (all [n][k], bf16)
__global__ void prep_weights(const float* __restrict__ W1, const float* __restrict__ W2,
                             const float* __restrict__ W3,
                             unsigned short* __restrict__ W1T,
                             unsigned short* __restrict__ W2T,
                             unsigned short* __restrict__ W3T){
    int i = blockIdx.x * 256 + threadIdx.x;
    if (i < 32768){
        int n = i >> 7, k = i & 127;
        W1T[i] = f2bf(W1[k * 256 + n]);
    } else if (i < 65536){
        int j = i - 32768; int n = j >> 8, k = j & 255;
        W2T[j] = f2bf(W2[k * 128 + n]);
    } else if (i < 196608){
        int j = i - 65536; int n = j >> 8, k = j & 255;
        W3T[j] = f2bf(W3[k * 512 + n]);
    }
}

// ---- main: 64 tokens/block, 8 waves split N; swapped-operand MFMA (D[n][token]) ----
__launch_bounds__(512, 4)
__global__ void main_kernel(const float* __restrict__ rho,
                            const float* __restrict__ c,
                            const float* __restrict__ w,
                            const int*  __restrict__ roads,
                            const unsigned short* __restrict__ W1T,
                            const float* __restrict__ b1,
                            const unsigned short* __restrict__ W2T,
                            const float* __restrict__ b2,
                            const unsigned short* __restrict__ W3T,
                            const float* __restrict__ b3,
                            const float* __restrict__ w21,
                            const float* __restrict__ b21s,
                            const float* __restrict__ w22,
                            const float* __restrict__ b22s,
                            float* __restrict__ pm,
                            float* __restrict__ pv)
{
    __shared__ __align__(16) unsigned char smem[81920];
    unsigned char* sXc = smem;            // [64][128] bf16 gathered c (16384 B)
    unsigned char* sH2 = smem + 16384;    // [64][256] bf16 f2 hidden  (32768 B)
    unsigned char* sX  = smem + 49152;    // [64][256] bf16 [rho|c_t]  (32768 B)
    float* sPm = (float*)smem;            // head partials (reuse sXc region in GEMM3)
    float* sPv = (float*)(smem + 2048);

    const int tid = threadIdx.x;
    const int t0  = blockIdx.x * 64;

    // stage: gather c rows (bf16) + rho tile (bf16)
    for (int u = tid; u < 64 * 32; u += 512){
        int row = u >> 5, ch = u & 31;
        int road = roads[t0 + row];
        float4 v = make_float4(0.f, 0.f, 0.f, 0.f);
        if (road > 0)
            v = reinterpret_cast<const float4*>(c + (size_t)(road - 1) * 128)[ch];
        ushort4 h;
        h.x = f2bf(v.x); h.y = f2bf(v.y); h.z = f2bf(v.z); h.w = f2bf(v.w);
        *reinterpret_cast<ushort4*>(sXc + swz(row, ch * 8, 256)) = h;

        float4 rv = reinterpret_cast<const float4*>(rho + (size_t)(t0 + row) * 128)[ch];
        ushort4 rh;
        rh.x = f2bf(rv.x); rh.y = f2bf(rv.y); rh.z = f2bf(rv.z); rh.w = f2bf(rv.w);
        *reinterpret_cast<ushort4*>(sX + swz(row, ch * 8, 512)) = rh;
    }
    __syncthreads();

    const int lane = tid & 63, wv = tid >> 6;   // wv 0..7
    const int lr = lane & 15, lg = lane >> 4;

    // ---- GEMM1: H2 = selu(Xc @ W1 + b1), K=128, N=256; wave owns n in [wv*32, wv*32+32) ----
    #pragma unroll
    for (int nc = 0; nc < 2; ++nc){
        const int n0 = wv * 32 + nc * 16;
        short8 b[4];
        #pragma unroll
        for (int kk = 0; kk < 4; ++kk)
            b[kk] = *reinterpret_cast<const short8*>(W1T + (n0 + lr) * 128 + kk * 32 + lg * 8);
        f32x4 acc[4] = {{0.f,0.f,0.f,0.f},{0.f,0.f,0.f,0.f},{0.f,0.f,0.f,0.f},{0.f,0.f,0.f,0.f}};
        #pragma unroll
        for (int kk = 0; kk < 4; ++kk){
            #pragma unroll
            for (int mt = 0; mt < 4; ++mt){
                short8 a = *reinterpret_cast<const short8*>(sXc + swz(mt * 16 + lr, kk * 64 + lg * 16, 256));
                acc[mt] = __builtin_amdgcn_mfma_f32_16x16x32_bf16(b[kk], a, acc[mt], 0, 0, 0);
            }
        }
        // lane holds n = n0 + lg*4 + r for token mt*16 + lr
        float4 bb = *reinterpret_cast<const float4*>(b1 + n0 + lg * 4);
        float bias[4] = {bb.x, bb.y, bb.z, bb.w};
        #pragma unroll
        for (int mt = 0; mt < 4; ++mt){
            ushort4 h;
            #pragma unroll
            for (int r = 0; r < 4; ++r){
                float vv = acc[mt][r] + bias[r];
                vv = (vv > 0.f) ? 1.0507009873554805f * vv
                                : 1.7580993408473766f * (__expf(vv) - 1.f);
                reinterpret_cast<unsigned short*>(&h)[r] = f2bf(vv);
            }
            *reinterpret_cast<ushort4*>(sH2 + swz(mt * 16 + lr, (n0 + lg * 4) * 2, 512)) = h;
        }
    }
    __syncthreads();

    // ---- GEMM2: c_t = H2 @ W2 + b2, K=256, N=128; wave owns n in [wv*16, wv*16+16) ----
    {
        const int n0 = wv * 16;
        short8 b[8];
        #pragma unroll
        for (int kk = 0; kk < 8; ++kk)
            b[kk] = *reinterpret_cast<const short8*>(W2T + (n0 + lr) * 256 + kk * 32 + lg * 8);
        f32x4 acc[4] = {{0.f,0.f,0.f,0.f},{0.f,0.f,0.f,0.f},{0.f,0.f,0.f,0.f},{0.f,0.f,0.f,0.f}};
        #pragma unroll
        for (int kk = 0; kk < 8; ++kk){
            #pragma unroll
            for (int mt = 0; mt < 4; ++mt){
                short8 a = *reinterpret_cast<const short8*>(sH2 + swz(mt * 16 + lr, kk * 64 + lg * 16, 512));
                acc[mt] = __builtin_amdgcn_mfma_f32_16x16x32_bf16(b[kk], a, acc[mt], 0, 0, 0);
            }
        }
        float4 bb = *reinterpret_cast<const float4*>(b2 + n0 + lg * 4);
        float bias[4] = {bb.x, bb.y, bb.z, bb.w};
        #pragma unroll
        for (int mt = 0; mt < 4; ++mt){
            ushort4 h;
            #pragma unroll
            for (int r = 0; r < 4; ++r){
                float vv = acc[mt][r] + bias[r];
                reinterpret_cast<unsigned short*>(&h)[r] = f2bf(vv);
            }
            *reinterpret_cast<ushort4*>(sX + swz(mt * 16 + lr, 256 + (n0 + lg * 4) * 2, 512)) = h;
        }
    }
    __syncthreads();

    // ---- GEMM3 + heads: h1 = relu(X @ W3 + b3); wave owns n in [wv*64, wv*64+64) ----
    float hm[4] = {0.f, 0.f, 0.f, 0.f};
    float hv[4] = {0.f, 0.f, 0.f, 0.f};
    #pragma unroll 2
    for (int nc = 0; nc < 4; ++nc){
        const int n0 = wv * 64 + nc * 16;
        short8 b[8];
        #pragma unroll
        for (int kk = 0; kk < 8; ++kk)
            b[kk] = *reinterpret_cast<const short8*>(W3T + (n0 + lr) * 256 + kk * 32 + lg * 8);
        f32x4 acc[4] = {{0.f,0.f,0.f,0.f},{0.f,0.f,0.f,0.f},{0.f,0.f,0.f,0.f},{0.f,0.f,0.f,0.f}};
        #pragma unroll
        for (int kk = 0; kk < 8; ++kk){
            #pragma unroll
            for (int mt = 0; mt < 4; ++mt){
                short8 a = *reinterpret_cast<const short8*>(sX + swz(mt * 16 + lr, kk * 64 + lg * 16, 512));
                acc[mt] = __builtin_amdgcn_mfma_f32_16x16x32_bf16(b[kk], a, acc[mt], 0, 0, 0);
            }
        }
        float4 b3q = *reinterpret_cast<const float4*>(b3  + n0 + lg * 4);
        float4 wmq = *reinterpret_cast<const float4*>(w21 + n0 + lg * 4);
        float4 wvq = *reinterpret_cast<const float4*>(w22 + n0 + lg * 4);
        float bias[4] = {b3q.x, b3q.y, b3q.z, b3q.w};
        float wm[4]   = {wmq.x, wmq.y, wmq.z, wmq.w};
        float wq[4]   = {wvq.x, wvq.y, wvq.z, wvq.w};
        #pragma unroll
        for (int mt = 0; mt < 4; ++mt){
            #pragma unroll
            for (int r = 0; r < 4; ++r){
                float h = fmaxf(acc[mt][r] + bias[r], 0.f);
                hm[mt] += h * wm[r];
                hv[mt] += h * wq[r];
            }
        }
    }
    // reduce across the 4 lg groups (lanes differing in bits 4..5 share token lr)
    #pragma unroll
    for (int mt = 0; mt < 4; ++mt){
        hm[mt] += __shfl_xor(hm[mt], 16, 64);
        hm[mt] += __shfl_xor(hm[mt], 32, 64);
        hv[mt] += __shfl_xor(hv[mt], 16, 64);
        hv[mt] += __shfl_xor(hv[mt], 32, 64);
    }
    if (lg == 0){
        #pragma unroll
        for (int mt = 0; mt < 4; ++mt){
            sPm[wv * 64 + mt * 16 + lr] = hm[mt];
            sPv[wv * 64 + mt * 16 + lr] = hv[mt];
        }
    }
    __syncthreads();
    if (tid < 64){
        float B21 = b21s[0], B22 = b22s[0];
        float m_ = B21, v_ = B22;
        #pragma unroll
        for (int k = 0; k < 8; ++k){
            m_ += sPm[k * 64 + tid];
            v_ += sPv[k * 64 + tid];
        }
        int t = t0 + tid;
        float lw = logf(w[t]);
        pm[t] = m_ + lw;
        pv[t] = v_ + 2.f * lw;
    }
}

// ---- reduce: per-batch logsumexp + epilogue ----
__global__ void reduce_kernel(const float* __restrict__ pm, const float* __restrict__ pv,
                              const float* __restrict__ l, float* __restrict__ out){
    int b = blockIdx.x;
    int tid = threadIdx.x;
    const float* Pm = pm + (size_t)b * 2048;
    const float* Pv = pv + (size_t)b * 2048;

    float mm = -1e30f, mv = -1e30f;
    for (int i = tid; i < 2048; i += 256){
        mm = fmaxf(mm, Pm[i]);
        mv = fmaxf(mv, Pv[i]);
    }
    __shared__ float redm[4], redv[4];
    #pragma unroll
    for (int off = 32; off > 0; off >>= 1){
        mm = fmaxf(mm, __shfl_xor(mm, off, 64));
        mv = fmaxf(mv, __shfl_xor(mv, off, 64));
    }
    int wv = tid >> 6;
    if ((tid & 63) == 0){ redm[wv] = mm; redv[wv] = mv; }
    __syncthreads();
    mm = fmaxf(fmaxf(redm[0], redm[1]), fmaxf(redm[2], redm[3]));
    mv = fmaxf(fmaxf(redv[0], redv[1]), fmaxf(redv[2], redv[3]));

    float sm = 0.f, sv = 0.f;
    for (int i = tid; i < 2048; i += 256){
        sm += expf(Pm[i] - mm);
        sv += expf(Pv[i] - mv);
    }
    #pragma unroll
    for (int off = 32; off > 0; off >>= 1){
        sm += __shfl_xor(sm, off, 64);
        sv += __shfl_xor(sv, off, 64);
    }
    __shared__ float red2m[4], red2v[4];
    if ((tid & 63) == 0){ red2m[wv] = sm; red2v[wv] = sv; }
    __syncthreads();
    if (tid == 0){
        sm = red2m[0] + red2m[1] + red2m[2] + red2m[3];
        sv = red2v[0] + red2v[1] + red2v[2] + red2v[3];
        float lsem = mm + logf(sm);
        float lsev = mv + logf(sv);
        float ll = logf(l[b]);
        out[b]      = ll - lsem;
        out[64 + b] = ll - 3.f * lsem - lsev;
    }
}

extern "C" void kernel_launch(void* const* d_in, const int* in_sizes, int n_in,
                              void* d_out, int out_size, void* d_ws, size_t ws_size,
                              hipStream_t stream){
    const float* rho   = (const float*)d_in[0];
    const float* c     = (const float*)d_in[1];
    const float* w     = (const float*)d_in[2];
    const float* l     = (const float*)d_in[3];
    const int*   roads = (const int*)  d_in[4];
    const float* f2_W1 = (const float*)d_in[5];
    const float* f2_b1 = (const float*)d_in[6];
    const float* f2_W2 = (const float*)d_in[7];
    const float* f2_b2 = (const float*)d_in[8];
    const float* f_W1  = (const float*)d_in[9];
    const float* f_b1  = (const float*)d_in[10];
    const float* f_W21 = (const float*)d_in[11];
    const float* f_b21 = (const float*)d_in[12];
    const float* f_W22 = (const float*)d_in[13];
    const float* f_b22 = (const float*)d_in[14];

    unsigned char* ws = (unsigned char*)d_ws;
    unsigned short* W1T = (unsigned short*)(ws);                 // 65536 B
    unsigned short* W2T = (unsigned short*)(ws + 65536);         // 65536 B
    unsigned short* W3T = (unsigned short*)(ws + 131072);        // 262144 B
    float* pm = (float*)(ws + 393216);                           // 524288 B
    float* pv = (float*)(ws + 393216 + 524288);                  // 524288 B

    prep_weights<<<768, 256, 0, stream>>>(f2_W1, f2_W2, f_W1, W1T, W2T, W3T);
    main_kernel<<<2048, 512, 0, stream>>>(rho, c, w, roads,
                                          W1T, f2_b1, W2T, f2_b2, W3T, f_b1,
                                          f_W21, f_b21, f_W22, f_b22, pm, pv);
    reduce_kernel<<<64, 256, 0, stream>>>(pm, pv, l, (float*)d_out);
}

// Round 7
// 161.852 us; speedup vs baseline: 1.5381x; 1.5381x over previous
//
#include <hip/hip_runtime.h>
#include <hip/hip_bf16.h>

typedef __attribute__((ext_vector_type(8))) short short8;
typedef __attribute__((ext_vector_type(4))) float f32x4;

__device__ __forceinline__ unsigned short f2bf(float f){
    unsigned u = __float_as_uint(f);
    unsigned r = (u + 0x7FFFu + ((u >> 16) & 1u)) >> 16;
    return (unsigned short)r;
}

// swizzled LDS byte offset for row-major bf16 tiles (stride 256B or 512B)
__device__ __forceinline__ unsigned swz(unsigned row, unsigned byte_in_row, unsigned stride){
    return (row * stride + byte_in_row) ^ ((row & 7u) << 4);
}

// ---- prep: transpose + bf16-convert weights ----
// W1T [256][128], W2T [128][256], W3T [512][256]  (all [n][k], bf16)
__global__ void prep_weights(const float* __restrict__ W1, const float* __restrict__ W2,
                             const float* __restrict__ W3,
                             unsigned short* __restrict__ W1T,
                             unsigned short* __restrict__ W2T,
                             unsigned short* __restrict__ W3T){
    int i = blockIdx.x * 256 + threadIdx.x;
    if (i < 32768){
        int n = i >> 7, k = i & 127;
        W1T[i] = f2bf(W1[k * 256 + n]);
    } else if (i < 65536){
        int j = i - 32768; int n = j >> 8, k = j & 255;
        W2T[j] = f2bf(W2[k * 128 + n]);
    } else if (i < 196608){
        int j = i - 65536; int n = j >> 8, k = j & 255;
        W3T[j] = f2bf(W3[k * 512 + n]);
    }
}

// ---- main: 64 tokens/block, 8 waves split N; swapped-operand MFMA (D[n][token]) ----
// launch_bounds second arg behaves as min BLOCKS/CU here (measured r5: (512,4) -> VGPR
// capped at 64 = 2048/32waves -> 340MB spills). (512,2) -> 16 waves/CU -> 128-VGPR cap.
__launch_bounds__(512, 2)
__global__ void main_kernel(const float* __restrict__ rho,
                            const float* __restrict__ c,
                            const float* __restrict__ w,
                            const int*  __restrict__ roads,
                            const unsigned short* __restrict__ W1T,
                            const float* __restrict__ b1,
                            const unsigned short* __restrict__ W2T,
                            const float* __restrict__ b2,
                            const unsigned short* __restrict__ W3T,
                            const float* __restrict__ b3,
                            const float* __restrict__ w21,
                            const float* __restrict__ b21s,
                            const float* __restrict__ w22,
                            const float* __restrict__ b22s,
                            float* __restrict__ pm,
                            float* __restrict__ pv)
{
    __shared__ __align__(16) unsigned char smem[81920];
    unsigned char* sXc = smem;            // [64][128] bf16 gathered c (16384 B)
    unsigned char* sH2 = smem + 16384;    // [64][256] bf16 f2 hidden  (32768 B)
    unsigned char* sX  = smem + 49152;    // [64][256] bf16 [rho|c_t]  (32768 B)
    float* sPm = (float*)smem;            // head partials (reuse sXc region in GEMM3)
    float* sPv = (float*)(smem + 2048);

    const int tid = threadIdx.x;
    const int t0  = blockIdx.x * 64;

    // stage: gather c rows (bf16) + rho tile (bf16)
    for (int u = tid; u < 64 * 32; u += 512){
        int row = u >> 5, ch = u & 31;
        int road = roads[t0 + row];
        float4 v = make_float4(0.f, 0.f, 0.f, 0.f);
        if (road > 0)
            v = reinterpret_cast<const float4*>(c + (size_t)(road - 1) * 128)[ch];
        ushort4 h;
        h.x = f2bf(v.x); h.y = f2bf(v.y); h.z = f2bf(v.z); h.w = f2bf(v.w);
        *reinterpret_cast<ushort4*>(sXc + swz(row, ch * 8, 256)) = h;

        float4 rv = reinterpret_cast<const float4*>(rho + (size_t)(t0 + row) * 128)[ch];
        ushort4 rh;
        rh.x = f2bf(rv.x); rh.y = f2bf(rv.y); rh.z = f2bf(rv.z); rh.w = f2bf(rv.w);
        *reinterpret_cast<ushort4*>(sX + swz(row, ch * 8, 512)) = rh;
    }
    __syncthreads();

    const int lane = tid & 63, wv = tid >> 6;   // wv 0..7
    const int lr = lane & 15, lg = lane >> 4;

    // ---- GEMM1: H2 = selu(Xc @ W1 + b1), K=128, N=256; wave owns n in [wv*32, wv*32+32) ----
    #pragma unroll
    for (int nc = 0; nc < 2; ++nc){
        const int n0 = wv * 32 + nc * 16;
        short8 b[4];
        #pragma unroll
        for (int kk = 0; kk < 4; ++kk)
            b[kk] = *reinterpret_cast<const short8*>(W1T + (n0 + lr) * 128 + kk * 32 + lg * 8);
        f32x4 acc[4] = {{0.f,0.f,0.f,0.f},{0.f,0.f,0.f,0.f},{0.f,0.f,0.f,0.f},{0.f,0.f,0.f,0.f}};
        #pragma unroll
        for (int kk = 0; kk < 4; ++kk){
            #pragma unroll
            for (int mt = 0; mt < 4; ++mt){
                short8 a = *reinterpret_cast<const short8*>(sXc + swz(mt * 16 + lr, kk * 64 + lg * 16, 256));
                acc[mt] = __builtin_amdgcn_mfma_f32_16x16x32_bf16(b[kk], a, acc[mt], 0, 0, 0);
            }
        }
        // lane holds n = n0 + lg*4 + r for token mt*16 + lr
        float4 bb = *reinterpret_cast<const float4*>(b1 + n0 + lg * 4);
        float bias[4] = {bb.x, bb.y, bb.z, bb.w};
        #pragma unroll
        for (int mt = 0; mt < 4; ++mt){
            ushort4 h;
            #pragma unroll
            for (int r = 0; r < 4; ++r){
                float vv = acc[mt][r] + bias[r];
                vv = (vv > 0.f) ? 1.0507009873554805f * vv
                                : 1.7580993408473766f * (__expf(vv) - 1.f);
                reinterpret_cast<unsigned short*>(&h)[r] = f2bf(vv);
            }
            *reinterpret_cast<ushort4*>(sH2 + swz(mt * 16 + lr, (n0 + lg * 4) * 2, 512)) = h;
        }
    }
    __syncthreads();

    // ---- GEMM2: c_t = H2 @ W2 + b2, K=256, N=128; wave owns n in [wv*16, wv*16+16) ----
    {
        const int n0 = wv * 16;
        short8 b[8];
        #pragma unroll
        for (int kk = 0; kk < 8; ++kk)
            b[kk] = *reinterpret_cast<const short8*>(W2T + (n0 + lr) * 256 + kk * 32 + lg * 8);
        f32x4 acc[4] = {{0.f,0.f,0.f,0.f},{0.f,0.f,0.f,0.f},{0.f,0.f,0.f,0.f},{0.f,0.f,0.f,0.f}};
        #pragma unroll
        for (int kk = 0; kk < 8; ++kk){
            #pragma unroll
            for (int mt = 0; mt < 4; ++mt){
                short8 a = *reinterpret_cast<const short8*>(sH2 + swz(mt * 16 + lr, kk * 64 + lg * 16, 512));
                acc[mt] = __builtin_amdgcn_mfma_f32_16x16x32_bf16(b[kk], a, acc[mt], 0, 0, 0);
            }
        }
        float4 bb = *reinterpret_cast<const float4*>(b2 + n0 + lg * 4);
        float bias[4] = {bb.x, bb.y, bb.z, bb.w};
        #pragma unroll
        for (int mt = 0; mt < 4; ++mt){
            ushort4 h;
            #pragma unroll
            for (int r = 0; r < 4; ++r){
                float vv = acc[mt][r] + bias[r];
                reinterpret_cast<unsigned short*>(&h)[r] = f2bf(vv);
            }
            *reinterpret_cast<ushort4*>(sX + swz(mt * 16 + lr, 256 + (n0 + lg * 4) * 2, 512)) = h;
        }
    }
    __syncthreads();

    // ---- GEMM3 + heads: h1 = relu(X @ W3 + b3); wave owns n in [wv*64, wv*64+64) ----
    float hm[4] = {0.f, 0.f, 0.f, 0.f};
    float hv[4] = {0.f, 0.f, 0.f, 0.f};
    #pragma unroll 2
    for (int nc = 0; nc < 4; ++nc){
        const int n0 = wv * 64 + nc * 16;
        short8 b[8];
        #pragma unroll
        for (int kk = 0; kk < 8; ++kk)
            b[kk] = *reinterpret_cast<const short8*>(W3T + (n0 + lr) * 256 + kk * 32 + lg * 8);
        f32x4 acc[4] = {{0.f,0.f,0.f,0.f},{0.f,0.f,0.f,0.f},{0.f,0.f,0.f,0.f},{0.f,0.f,0.f,0.f}};
        #pragma unroll
        for (int kk = 0; kk < 8; ++kk){
            #pragma unroll
            for (int mt = 0; mt < 4; ++mt){
                short8 a = *reinterpret_cast<const short8*>(sX + swz(mt * 16 + lr, kk * 64 + lg * 16, 512));
                acc[mt] = __builtin_amdgcn_mfma_f32_16x16x32_bf16(b[kk], a, acc[mt], 0, 0, 0);
            }
        }
        float4 b3q = *reinterpret_cast<const float4*>(b3  + n0 + lg * 4);
        float4 wmq = *reinterpret_cast<const float4*>(w21 + n0 + lg * 4);
        float4 wvq = *reinterpret_cast<const float4*>(w22 + n0 + lg * 4);
        float bias[4] = {b3q.x, b3q.y, b3q.z, b3q.w};
        float wm[4]   = {wmq.x, wmq.y, wmq.z, wmq.w};
        float wq[4]   = {wvq.x, wvq.y, wvq.z, wvq.w};
        #pragma unroll
        for (int mt = 0; mt < 4; ++mt){
            #pragma unroll
            for (int r = 0; r < 4; ++r){
                float h = fmaxf(acc[mt][r] + bias[r], 0.f);
                hm[mt] += h * wm[r];
                hv[mt] += h * wq[r];
            }
        }
    }
    // reduce across the 4 lg groups (lanes differing in bits 4..5 share token lr)
    #pragma unroll
    for (int mt = 0; mt < 4; ++mt){
        hm[mt] += __shfl_xor(hm[mt], 16, 64);
        hm[mt] += __shfl_xor(hm[mt], 32, 64);
        hv[mt] += __shfl_xor(hv[mt], 16, 64);
        hv[mt] += __shfl_xor(hv[mt], 32, 64);
    }
    if (lg == 0){
        #pragma unroll
        for (int mt = 0; mt < 4; ++mt){
            sPm[wv * 64 + mt * 16 + lr] = hm[mt];
            sPv[wv * 64 + mt * 16 + lr] = hv[mt];
        }
    }
    __syncthreads();
    if (tid < 64){
        float B21 = b21s[0], B22 = b22s[0];
        float m_ = B21, v_ = B22;
        #pragma unroll
        for (int k = 0; k < 8; ++k){
            m_ += sPm[k * 64 + tid];
            v_ += sPv[k * 64 + tid];
        }
        int t = t0 + tid;
        float lw = logf(w[t]);
        pm[t] = m_ + lw;
        pv[t] = v_ + 2.f * lw;
    }
}

// ---- reduce: per-batch logsumexp + epilogue ----
__global__ void reduce_kernel(const float* __restrict__ pm, const float* __restrict__ pv,
                              const float* __restrict__ l, float* __restrict__ out){
    int b = blockIdx.x;
    int tid = threadIdx.x;
    const float* Pm = pm + (size_t)b * 2048;
    const float* Pv = pv + (size_t)b * 2048;

    float mm = -1e30f, mv = -1e30f;
    for (int i = tid; i < 2048; i += 256){
        mm = fmaxf(mm, Pm[i]);
        mv = fmaxf(mv, Pv[i]);
    }
    __shared__ float redm[4], redv[4];
    #pragma unroll
    for (int off = 32; off > 0; off >>= 1){
        mm = fmaxf(mm, __shfl_xor(mm, off, 64));
        mv = fmaxf(mv, __shfl_xor(mv, off, 64));
    }
    int wv = tid >> 6;
    if ((tid & 63) == 0){ redm[wv] = mm; redv[wv] = mv; }
    __syncthreads();
    mm = fmaxf(fmaxf(redm[0], redm[1]), fmaxf(redm[2], redm[3]));
    mv = fmaxf(fmaxf(redv[0], redv[1]), fmaxf(redv[2], redv[3]));

    float sm = 0.f, sv = 0.f;
    for (int i = tid; i < 2048; i += 256){
        sm += expf(Pm[i] - mm);
        sv += expf(Pv[i] - mv);
    }
    #pragma unroll
    for (int off = 32; off > 0; off >>= 1){
        sm += __shfl_xor(sm, off, 64);
        sv += __shfl_xor(sv, off, 64);
    }
    __shared__ float red2m[4], red2v[4];
    if ((tid & 63) == 0){ red2m[wv] = sm; red2v[wv] = sv; }
    __syncthreads();
    if (tid == 0){
        sm = red2m[0] + red2m[1] + red2m[2] + red2m[3];
        sv = red2v[0] + red2v[1] + red2v[2] + red2v[3];
        float lsem = mm + logf(sm);
        float lsev = mv + logf(sv);
        float ll = logf(l[b]);
        out[b]      = ll - lsem;
        out[64 + b] = ll - 3.f * lsem - lsev;
    }
}

extern "C" void kernel_launch(void* const* d_in, const int* in_sizes, int n_in,
                              void* d_out, int out_size, void* d_ws, size_t ws_size,
                              hipStream_t stream){
    const float* rho   = (const float*)d_in[0];
    const float* c     = (const float*)d_in[1];
    const float* w     = (const float*)d_in[2];
    const float* l     = (const float*)d_in[3];
    const int*   roads = (const int*)  d_in[4];
    const float* f2_W1 = (const float*)d_in[5];
    const float* f2_b1 = (const float*)d_in[6];
    const float* f2_W2 = (const float*)d_in[7];
    const float* f2_b2 = (const float*)d_in[8];
    const float* f_W1  = (const float*)d_in[9];
    const float* f_b1  = (const float*)d_in[10];
    const float* f_W21 = (const float*)d_in[11];
    const float* f_b21 = (const float*)d_in[12];
    const float* f_W22 = (const float*)d_in[13];
    const float* f_b22 = (const float*)d_in[14];

    unsigned char* ws = (unsigned char*)d_ws;
    unsigned short* W1T = (unsigned short*)(ws);                 // 65536 B
    unsigned short* W2T = (unsigned short*)(ws + 65536);         // 65536 B
    unsigned short* W3T = (unsigned short*)(ws + 131072);        // 262144 B
    float* pm = (float*)(ws + 393216);                           // 524288 B
    float* pv = (float*)(ws + 393216 + 524288);                  // 524288 B

    prep_weights<<<768, 256, 0, stream>>>(f2_W1, f2_W2, f_W1, W1T, W2T, W3T);
    main_kernel<<<2048, 512, 0, stream>>>(rho, c, w, roads,
                                          W1T, f2_b1, W2T, f2_b2, W3T, f_b1,
                                          f_W21, f_b21, f_W22, f_b22, pm, pv);
    reduce_kernel<<<64, 256, 0, stream>>>(pm, pv, l, (float*)d_out);
}

// Round 9
// 161.746 us; speedup vs baseline: 1.5391x; 1.0007x over previous
//
#include <hip/hip_runtime.h>
#include <hip/hip_bf16.h>

typedef __attribute__((ext_vector_type(8))) short short8;
typedef __attribute__((ext_vector_type(4))) float f32x4;

__device__ __forceinline__ unsigned short f2bf(float f){
    unsigned u = __float_as_uint(f);
    unsigned r = (u + 0x7FFFu + ((u >> 16) & 1u)) >> 16;
    return (unsigned short)r;
}

// swizzled LDS byte offset for row-major bf16 tiles (stride 256B or 512B)
__device__ __forceinline__ unsigned swz(unsigned row, unsigned byte_in_row, unsigned stride){
    return (row * stride + byte_in_row) ^ ((row & 7u) << 4);
}

// ---- prep: transpose + bf16-convert weights ----
// W1T [256][128], W2T [128][256], W3T [512][256]  (all [n][k], bf16)
__global__ void prep_weights(const float* __restrict__ W1, const float* __restrict__ W2,
                             const float* __restrict__ W3,
                             unsigned short* __restrict__ W1T,
                             unsigned short* __restrict__ W2T,
                             unsigned short* __restrict__ W3T){
    int i = blockIdx.x * 256 + threadIdx.x;
    if (i < 32768){
        int n = i >> 7, k = i & 127;
        W1T[i] = f2bf(W1[k * 256 + n]);
    } else if (i < 65536){
        int j = i - 32768; int n = j >> 8, k = j & 255;
        W2T[j] = f2bf(W2[k * 128 + n]);
    } else if (i < 196608){
        int j = i - 65536; int n = j >> 8, k = j & 255;
        W3T[j] = f2bf(W3[k * 512 + n]);
    }
}

// ---- main: 64 tokens/block, 8 waves split N; swapped-operand MFMA (D[n][token]) ----
// LDS = 64KB so 2 blocks/CU (128KB) fit: r7 showed 2x80KB = exactly 160KB does NOT
// co-reside (driver reserve) -> occupancy stuck at 1 block (22%).
// launch_bounds (512,2): VGPR cap 128 (r5: (512,4) capped at 64 -> 340MB spills).
__launch_bounds__(512, 2)
__global__ void main_kernel(const float* __restrict__ rho,
                            const float* __restrict__ c,
                            const float* __restrict__ w,
                            const int*  __restrict__ roads,
                            const unsigned short* __restrict__ W1T,
                            const float* __restrict__ b1,
                            const unsigned short* __restrict__ W2T,
                            const float* __restrict__ b2,
                            const unsigned short* __restrict__ W3T,
                            const float* __restrict__ b3,
                            const float* __restrict__ w21,
                            const float* __restrict__ b21s,
                            const float* __restrict__ w22,
                            const float* __restrict__ b22s,
                            float* __restrict__ pm,
                            float* __restrict__ pv)
{
    __shared__ __align__(16) unsigned char smem[65536];
    unsigned char* sXc  = smem;            // [64][128] bf16: gathered c, RECYCLED as c_t after GEMM1
    unsigned char* sH2  = smem + 16384;    // [64][256] bf16 f2 hidden (32KB); dead in GEMM3
    unsigned char* sRho = smem + 49152;    // [64][128] bf16 rho tile (16KB)
    float* sPm = (float*)(smem + 16384);   // head partials overlay sH2 region (dead in GEMM3)
    float* sPv = (float*)(smem + 16384 + 2048);

    const int tid = threadIdx.x;
    const int t0  = blockIdx.x * 64;

    // stage: gather c rows (bf16) + rho tile (bf16)
    for (int u = tid; u < 64 * 32; u += 512){
        int row = u >> 5, ch = u & 31;
        int road = roads[t0 + row];
        float4 v = make_float4(0.f, 0.f, 0.f, 0.f);
        if (road > 0)
            v = reinterpret_cast<const float4*>(c + (size_t)(road - 1) * 128)[ch];
        ushort4 h;
        h.x = f2bf(v.x); h.y = f2bf(v.y); h.z = f2bf(v.z); h.w = f2bf(v.w);
        *reinterpret_cast<ushort4*>(sXc + swz(row, ch * 8, 256)) = h;

        float4 rv = reinterpret_cast<const float4*>(rho + (size_t)(t0 + row) * 128)[ch];
        ushort4 rh;
        rh.x = f2bf(rv.x); rh.y = f2bf(rv.y); rh.z = f2bf(rv.z); rh.w = f2bf(rv.w);
        *reinterpret_cast<ushort4*>(sRho + swz(row, ch * 8, 256)) = rh;
    }
    __syncthreads();

    const int lane = tid & 63, wv = tid >> 6;   // wv 0..7
    const int lr = lane & 15, lg = lane >> 4;

    // ---- GEMM1: H2 = selu(Xc @ W1 + b1), K=128, N=256; wave owns n in [wv*32, wv*32+32) ----
    #pragma unroll
    for (int nc = 0; nc < 2; ++nc){
        const int n0 = wv * 32 + nc * 16;
        short8 b[4];
        #pragma unroll
        for (int kk = 0; kk < 4; ++kk)
            b[kk] = *reinterpret_cast<const short8*>(W1T + (n0 + lr) * 128 + kk * 32 + lg * 8);
        f32x4 acc[4] = {{0.f,0.f,0.f,0.f},{0.f,0.f,0.f,0.f},{0.f,0.f,0.f,0.f},{0.f,0.f,0.f,0.f}};
        #pragma unroll
        for (int kk = 0; kk < 4; ++kk){
            #pragma unroll
            for (int mt = 0; mt < 4; ++mt){
                short8 a = *reinterpret_cast<const short8*>(sXc + swz(mt * 16 + lr, kk * 64 + lg * 16, 256));
                acc[mt] = __builtin_amdgcn_mfma_f32_16x16x32_bf16(b[kk], a, acc[mt], 0, 0, 0);
            }
        }
        // lane holds n = n0 + lg*4 + r for token mt*16 + lr
        float4 bb = *reinterpret_cast<const float4*>(b1 + n0 + lg * 4);
        float bias[4] = {bb.x, bb.y, bb.z, bb.w};
        #pragma unroll
        for (int mt = 0; mt < 4; ++mt){
            ushort4 h;
            #pragma unroll
            for (int r = 0; r < 4; ++r){
                float vv = acc[mt][r] + bias[r];
                vv = (vv > 0.f) ? 1.0507009873554805f * vv
                                : 1.7580993408473766f * (__expf(vv) - 1.f);
                reinterpret_cast<unsigned short*>(&h)[r] = f2bf(vv);
            }
            *reinterpret_cast<ushort4*>(sH2 + swz(mt * 16 + lr, (n0 + lg * 4) * 2, 512)) = h;
        }
    }
    __syncthreads();

    // ---- GEMM2: c_t = H2 @ W2 + b2, K=256, N=128; wave owns n in [wv*16, wv*16+16) ----
    // output c_t goes into the RECYCLED sXc buffer ([64][128] bf16, stride 256)
    {
        const int n0 = wv * 16;
        short8 b[8];
        #pragma unroll
        for (int kk = 0; kk < 8; ++kk)
            b[kk] = *reinterpret_cast<const short8*>(W2T + (n0 + lr) * 256 + kk * 32 + lg * 8);
        f32x4 acc[4] = {{0.f,0.f,0.f,0.f},{0.f,0.f,0.f,0.f},{0.f,0.f,0.f,0.f},{0.f,0.f,0.f,0.f}};
        #pragma unroll
        for (int kk = 0; kk < 8; ++kk){
            #pragma unroll
            for (int mt = 0; mt < 4; ++mt){
                short8 a = *reinterpret_cast<const short8*>(sH2 + swz(mt * 16 + lr, kk * 64 + lg * 16, 512));
                acc[mt] = __builtin_amdgcn_mfma_f32_16x16x32_bf16(b[kk], a, acc[mt], 0, 0, 0);
            }
        }
        float4 bb = *reinterpret_cast<const float4*>(b2 + n0 + lg * 4);
        float bias[4] = {bb.x, bb.y, bb.z, bb.w};
        #pragma unroll
        for (int mt = 0; mt < 4; ++mt){
            ushort4 h;
            #pragma unroll
            for (int r = 0; r < 4; ++r){
                float vv = acc[mt][r] + bias[r];
                reinterpret_cast<unsigned short*>(&h)[r] = f2bf(vv);
            }
            *reinterpret_cast<ushort4*>(sXc + swz(mt * 16 + lr, (n0 + lg * 4) * 2, 256)) = h;
        }
    }
    __syncthreads();

    // ---- GEMM3 + heads: h1 = relu([rho|c_t] @ W3 + b3); wave owns n in [wv*64, wv*64+64) ----
    // kk 0-3: rho from sRho; kk 4-7: c_t from recycled sXc (both stride-256 tiles)
    float hm[4] = {0.f, 0.f, 0.f, 0.f};
    float hv[4] = {0.f, 0.f, 0.f, 0.f};
    #pragma unroll 2
    for (int nc = 0; nc < 4; ++nc){
        const int n0 = wv * 64 + nc * 16;
        short8 b[8];
        #pragma unroll
        for (int kk = 0; kk < 8; ++kk)
            b[kk] = *reinterpret_cast<const short8*>(W3T + (n0 + lr) * 256 + kk * 32 + lg * 8);
        f32x4 acc[4] = {{0.f,0.f,0.f,0.f},{0.f,0.f,0.f,0.f},{0.f,0.f,0.f,0.f},{0.f,0.f,0.f,0.f}};
        #pragma unroll
        for (int kk = 0; kk < 8; ++kk){
            const unsigned char* src = (kk < 4) ? sRho : sXc;
            #pragma unroll
            for (int mt = 0; mt < 4; ++mt){
                short8 a = *reinterpret_cast<const short8*>(src + swz(mt * 16 + lr, (kk & 3) * 64 + lg * 16, 256));
                acc[mt] = __builtin_amdgcn_mfma_f32_16x16x32_bf16(b[kk], a, acc[mt], 0, 0, 0);
            }
        }
        float4 b3q = *reinterpret_cast<const float4*>(b3  + n0 + lg * 4);
        float4 wmq = *reinterpret_cast<const float4*>(w21 + n0 + lg * 4);
        float4 wvq = *reinterpret_cast<const float4*>(w22 + n0 + lg * 4);
        float bias[4] = {b3q.x, b3q.y, b3q.z, b3q.w};
        float wm[4]   = {wmq.x, wmq.y, wmq.z, wmq.w};
        float wq[4]   = {wvq.x, wvq.y, wvq.z, wvq.w};
        #pragma unroll
        for (int mt = 0; mt < 4; ++mt){
            #pragma unroll
            for (int r = 0; r < 4; ++r){
                float h = fmaxf(acc[mt][r] + bias[r], 0.f);
                hm[mt] += h * wm[r];
                hv[mt] += h * wq[r];
            }
        }
    }
    // reduce across the 4 lg groups (lanes differing in bits 4..5 share token lr)
    #pragma unroll
    for (int mt = 0; mt < 4; ++mt){
        hm[mt] += __shfl_xor(hm[mt], 16, 64);
        hm[mt] += __shfl_xor(hm[mt], 32, 64);
        hv[mt] += __shfl_xor(hv[mt], 16, 64);
        hv[mt] += __shfl_xor(hv[mt], 32, 64);
    }
    if (lg == 0){
        #pragma unroll
        for (int mt = 0; mt < 4; ++mt){
            sPm[wv * 64 + mt * 16 + lr] = hm[mt];
            sPv[wv * 64 + mt * 16 + lr] = hv[mt];
        }
    }
    __syncthreads();
    if (tid < 64){
        float B21 = b21s[0], B22 = b22s[0];
        float m_ = B21, v_ = B22;
        #pragma unroll
        for (int k = 0; k < 8; ++k){
            m_ += sPm[k * 64 + tid];
            v_ += sPv[k * 64 + tid];
        }
        int t = t0 + tid;
        float lw = logf(w[t]);
        pm[t] = m_ + lw;
        pv[t] = v_ + 2.f * lw;
    }
}

// ---- reduce: per-batch logsumexp + epilogue ----
__global__ void reduce_kernel(const float* __restrict__ pm, const float* __restrict__ pv,
                              const float* __restrict__ l, float* __restrict__ out){
    int b = blockIdx.x;
    int tid = threadIdx.x;
    const float* Pm = pm + (size_t)b * 2048;
    const float* Pv = pv + (size_t)b * 2048;

    float mm = -1e30f, mv = -1e30f;
    for (int i = tid; i < 2048; i += 256){
        mm = fmaxf(mm, Pm[i]);
        mv = fmaxf(mv, Pv[i]);
    }
    __shared__ float redm[4], redv[4];
    #pragma unroll
    for (int off = 32; off > 0; off >>= 1){
        mm = fmaxf(mm, __shfl_xor(mm, off, 64));
        mv = fmaxf(mv, __shfl_xor(mv, off, 64));
    }
    int wv = tid >> 6;
    if ((tid & 63) == 0){ redm[wv] = mm; redv[wv] = mv; }
    __syncthreads();
    mm = fmaxf(fmaxf(redm[0], redm[1]), fmaxf(redm[2], redm[3]));
    mv = fmaxf(fmaxf(redv[0], redv[1]), fmaxf(redv[2], redv[3]));

    float sm = 0.f, sv = 0.f;
    for (int i = tid; i < 2048; i += 256){
        sm += expf(Pm[i] - mm);
        sv += expf(Pv[i] - mv);
    }
    #pragma unroll
    for (int off = 32; off > 0; off >>= 1){
        sm += __shfl_xor(sm, off, 64);
        sv += __shfl_xor(sv, off, 64);
    }
    __shared__ float red2m[4], red2v[4];
    if ((tid & 63) == 0){ red2m[wv] = sm; red2v[wv] = sv; }
    __syncthreads();
    if (tid == 0){
        sm = red2m[0] + red2m[1] + red2m[2] + red2m[3];
        sv = red2v[0] + red2v[1] + red2v[2] + red2v[3];
        float lsem = mm + logf(sm);
        float lsev = mv + logf(sv);
        float ll = logf(l[b]);
        out[b]      = ll - lsem;
        out[64 + b] = ll - 3.f * lsem - lsev;
    }
}

extern "C" void kernel_launch(void* const* d_in, const int* in_sizes, int n_in,
                              void* d_out, int out_size, void* d_ws, size_t ws_size,
                              hipStream_t stream){
    const float* rho   = (const float*)d_in[0];
    const float* c     = (const float*)d_in[1];
    const float* w     = (const float*)d_in[2];
    const float* l     = (const float*)d_in[3];
    const int*   roads = (const int*)  d_in[4];
    const float* f2_W1 = (const float*)d_in[5];
    const float* f2_b1 = (const float*)d_in[6];
    const float* f2_W2 = (const float*)d_in[7];
    const float* f2_b2 = (const float*)d_in[8];
    const float* f_W1  = (const float*)d_in[9];
    const float* f_b1  = (const float*)d_in[10];
    const float* f_W21 = (const float*)d_in[11];
    const float* f_b21 = (const float*)d_in[12];
    const float* f_W22 = (const float*)d_in[13];
    const float* f_b22 = (const float*)d_in[14];

    unsigned char* ws = (unsigned char*)d_ws;
    unsigned short* W1T = (unsigned short*)(ws);                 // 65536 B
    unsigned short* W2T = (unsigned short*)(ws + 65536);         // 65536 B
    unsigned short* W3T = (unsigned short*)(ws + 131072);        // 262144 B
    float* pm = (float*)(ws + 393216);                           // 524288 B
    float* pv = (float*)(ws + 393216 + 524288);                  // 524288 B

    prep_weights<<<768, 256, 0, stream>>>(f2_W1, f2_W2, f_W1, W1T, W2T, W3T);
    main_kernel<<<2048, 512, 0, stream>>>(rho, c, w, roads,
                                          W1T, f2_b1, W2T, f2_b2, W3T, f_b1,
                                          f_W21, f_b21, f_W22, f_b22, pm, pv);
    reduce_kernel<<<64, 256, 0, stream>>>(pm, pv, l, (float*)d_out);
}

// Round 14
// 129.082 us; speedup vs baseline: 1.9286x; 1.2530x over previous
//
#include <hip/hip_runtime.h>
#include <hip/hip_bf16.h>

typedef __attribute__((ext_vector_type(8))) short short8;
typedef __attribute__((ext_vector_type(4))) float f32x4;

__device__ __forceinline__ unsigned short f2bf(float f){
    unsigned u = __float_as_uint(f);
    unsigned r = (u + 0x7FFFu + ((u >> 16) & 1u)) >> 16;
    return (unsigned short)r;
}

// swizzled LDS byte offset for row-major bf16 tiles (stride 256B or 512B).
// XOR (row&15)<<4: bijective within a row; 16B reads by 16-lane quarter-waves
// cover all 32 banks exactly 2x -> conflict-free (old (row&7)<<4 left 8-way
// bank-start aliasing: r9 SQ_LDS_BANK_CONFLICT 6.16M cycles).
__device__ __forceinline__ unsigned swz(unsigned row, unsigned byte_in_row, unsigned stride){
    return row * stride + (byte_in_row ^ ((row & 15u) << 4));
}

// ---- prep: transpose + bf16-convert weights ----
// W1T [256][128], W2T [128][256], W3T [512][256]  (all [n][k], bf16)
__global__ void prep_weights(const float* __restrict__ W1, const float* __restrict__ W2,
                             const float* __restrict__ W3,
                             unsigned short* __restrict__ W1T,
                             unsigned short* __restrict__ W2T,
                             unsigned short* __restrict__ W3T){
    int i = blockIdx.x * 256 + threadIdx.x;
    if (i < 32768){
        int n = i >> 7, k = i & 127;
        W1T[i] = f2bf(W1[k * 256 + n]);
    } else if (i < 65536){
        int j = i - 32768; int n = j >> 8, k = j & 255;
        W2T[j] = f2bf(W2[k * 128 + n]);
    } else if (i < 196608){
        int j = i - 65536; int n = j >> 8, k = j & 255;
        W3T[j] = f2bf(W3[k * 512 + n]);
    }
}

// ---- main: 64 tokens/block, 8 waves split N; swapped-operand MFMA (D[n][token]) ----
// Occupancy model (r2/r5/r7/r9 evidence): wave slots granted on arch+AGPR total;
// 4 waves/SIMD needs total <= 128. Keep arch VGPR lean: B staged in 4-frag
// chunks (unroll 1 on outer loops), target arch ~100 + 16 AGPR acc.
__launch_bounds__(512, 2)
__global__ void main_kernel(const float* __restrict__ rho,
                            const float* __restrict__ c,
                            const float* __restrict__ w,
                            const int*  __restrict__ roads,
                            const unsigned short* __restrict__ W1T,
                            const float* __restrict__ b1,
                            const unsigned short* __restrict__ W2T,
                            const float* __restrict__ b2,
                            const unsigned short* __restrict__ W3T,
                            const float* __restrict__ b3,
                            const float* __restrict__ w21,
                            const float* __restrict__ b21s,
                            const float* __restrict__ w22,
                            const float* __restrict__ b22s,
                            float* __restrict__ pm,
                            float* __restrict__ pv)
{
    __shared__ __align__(16) unsigned char smem[65536];
    unsigned char* sXc  = smem;            // [64][128] bf16: gathered c, RECYCLED as c_t after GEMM1
    unsigned char* sH2  = smem + 16384;    // [64][256] bf16 f2 hidden (32KB); dead in GEMM3
    unsigned char* sRho = smem + 49152;    // [64][128] bf16 rho tile (16KB)
    float* sPm = (float*)(smem + 16384);   // head partials overlay sH2 region (dead in GEMM3)
    float* sPv = (float*)(smem + 16384 + 2048);

    const int tid = threadIdx.x;
    const int t0  = blockIdx.x * 64;

    // stage: gather c rows (bf16) + rho tile (bf16)
    for (int u = tid; u < 64 * 32; u += 512){
        int row = u >> 5, ch = u & 31;
        int road = roads[t0 + row];
        float4 v = make_float4(0.f, 0.f, 0.f, 0.f);
        if (road > 0)
            v = reinterpret_cast<const float4*>(c + (size_t)(road - 1) * 128)[ch];
        ushort4 h;
        h.x = f2bf(v.x); h.y = f2bf(v.y); h.z = f2bf(v.z); h.w = f2bf(v.w);
        *reinterpret_cast<ushort4*>(sXc + swz(row, ch * 8, 256)) = h;

        float4 rv = reinterpret_cast<const float4*>(rho + (size_t)(t0 + row) * 128)[ch];
        ushort4 rh;
        rh.x = f2bf(rv.x); rh.y = f2bf(rv.y); rh.z = f2bf(rv.z); rh.w = f2bf(rv.w);
        *reinterpret_cast<ushort4*>(sRho + swz(row, ch * 8, 256)) = rh;
    }
    __syncthreads();

    const int lane = tid & 63, wv = tid >> 6;   // wv 0..7
    const int lr = lane & 15, lg = lane >> 4;

    // ---- GEMM1: H2 = selu(Xc @ W1 + b1), K=128, N=256; wave owns n in [wv*32, wv*32+32) ----
    #pragma unroll 1
    for (int nc = 0; nc < 2; ++nc){
        const int n0 = wv * 32 + nc * 16;
        short8 b[4];
        #pragma unroll
        for (int kk = 0; kk < 4; ++kk)
            b[kk] = *reinterpret_cast<const short8*>(W1T + (n0 + lr) * 128 + kk * 32 + lg * 8);
        f32x4 acc[4] = {{0.f,0.f,0.f,0.f},{0.f,0.f,0.f,0.f},{0.f,0.f,0.f,0.f},{0.f,0.f,0.f,0.f}};
        #pragma unroll
        for (int kk = 0; kk < 4; ++kk){
            #pragma unroll
            for (int mt = 0; mt < 4; ++mt){
                short8 a = *reinterpret_cast<const short8*>(sXc + swz(mt * 16 + lr, kk * 64 + lg * 16, 256));
                acc[mt] = __builtin_amdgcn_mfma_f32_16x16x32_bf16(b[kk], a, acc[mt], 0, 0, 0);
            }
        }
        // lane holds n = n0 + lg*4 + r for token mt*16 + lr
        float4 bb = *reinterpret_cast<const float4*>(b1 + n0 + lg * 4);
        #pragma unroll
        for (int mt = 0; mt < 4; ++mt){
            ushort4 h;
            #pragma unroll
            for (int r = 0; r < 4; ++r){
                float vv = acc[mt][r] + (&bb.x)[r];
                vv = (vv > 0.f) ? 1.0507009873554805f * vv
                                : 1.7580993408473766f * (__expf(vv) - 1.f);
                reinterpret_cast<unsigned short*>(&h)[r] = f2bf(vv);
            }
            *reinterpret_cast<ushort4*>(sH2 + swz(mt * 16 + lr, (n0 + lg * 4) * 2, 512)) = h;
        }
    }
    __syncthreads();

    // ---- GEMM2: c_t = H2 @ W2 + b2, K=256, N=128; wave owns n in [wv*16, wv*16+16) ----
    // output c_t -> RECYCLED sXc ([64][128] bf16, stride 256). B staged in 4-frag chunks.
    {
        const int n0 = wv * 16;
        f32x4 acc[4] = {{0.f,0.f,0.f,0.f},{0.f,0.f,0.f,0.f},{0.f,0.f,0.f,0.f},{0.f,0.f,0.f,0.f}};
        #pragma unroll 1
        for (int h4 = 0; h4 < 2; ++h4){
            short8 b[4];
            #pragma unroll
            for (int kk = 0; kk < 4; ++kk)
                b[kk] = *reinterpret_cast<const short8*>(W2T + (n0 + lr) * 256 + (h4 * 4 + kk) * 32 + lg * 8);
            #pragma unroll
            for (int kk = 0; kk < 4; ++kk){
                #pragma unroll
                for (int mt = 0; mt < 4; ++mt){
                    short8 a = *reinterpret_cast<const short8*>(sH2 + swz(mt * 16 + lr, (h4 * 4 + kk) * 64 + lg * 16, 512));
                    acc[mt] = __builtin_amdgcn_mfma_f32_16x16x32_bf16(b[kk], a, acc[mt], 0, 0, 0);
                }
            }
        }
        float4 bb = *reinterpret_cast<const float4*>(b2 + n0 + lg * 4);
        #pragma unroll
        for (int mt = 0; mt < 4; ++mt){
            ushort4 h;
            #pragma unroll
            for (int r = 0; r < 4; ++r){
                float vv = acc[mt][r] + (&bb.x)[r];
                reinterpret_cast<unsigned short*>(&h)[r] = f2bf(vv);
            }
            *reinterpret_cast<ushort4*>(sXc + swz(mt * 16 + lr, (n0 + lg * 4) * 2, 256)) = h;
        }
    }
    __syncthreads();

    // ---- GEMM3 + heads: h1 = relu([rho|c_t] @ W3 + b3); wave owns n in [wv*64, wv*64+64) ----
    // kk-half 0: rho from sRho; kk-half 1: c_t from recycled sXc (both stride-256 tiles)
    float hm[4] = {0.f, 0.f, 0.f, 0.f};
    float hv[4] = {0.f, 0.f, 0.f, 0.f};
    #pragma unroll 1
    for (int nc = 0; nc < 4; ++nc){
        const int n0 = wv * 64 + nc * 16;
        f32x4 acc[4] = {{0.f,0.f,0.f,0.f},{0.f,0.f,0.f,0.f},{0.f,0.f,0.f,0.f},{0.f,0.f,0.f,0.f}};
        #pragma unroll 1
        for (int h4 = 0; h4 < 2; ++h4){
            const unsigned char* src = h4 ? sXc : sRho;
            short8 b[4];
            #pragma unroll
            for (int kk = 0; kk < 4; ++kk)
                b[kk] = *reinterpret_cast<const short8*>(W3T + (n0 + lr) * 256 + (h4 * 4 + kk) * 32 + lg * 8);
            #pragma unroll
            for (int kk = 0; kk < 4; ++kk){
                #pragma unroll
                for (int mt = 0; mt < 4; ++mt){
                    short8 a = *reinterpret_cast<const short8*>(src + swz(mt * 16 + lr, kk * 64 + lg * 16, 256));
                    acc[mt] = __builtin_amdgcn_mfma_f32_16x16x32_bf16(b[kk], a, acc[mt], 0, 0, 0);
                }
            }
        }
        float4 b3q = *reinterpret_cast<const float4*>(b3  + n0 + lg * 4);
        float4 wmq = *reinterpret_cast<const float4*>(w21 + n0 + lg * 4);
        float4 wvq = *reinterpret_cast<const float4*>(w22 + n0 + lg * 4);
        #pragma unroll
        for (int mt = 0; mt < 4; ++mt){
            #pragma unroll
            for (int r = 0; r < 4; ++r){
                float h = fmaxf(acc[mt][r] + (&b3q.x)[r], 0.f);
                hm[mt] += h * (&wmq.x)[r];
                hv[mt] += h * (&wvq.x)[r];
            }
        }
    }
    // reduce across the 4 lg groups (lanes differing in bits 4..5 share token lr)
    #pragma unroll
    for (int mt = 0; mt < 4; ++mt){
        hm[mt] += __shfl_xor(hm[mt], 16, 64);
        hm[mt] += __shfl_xor(hm[mt], 32, 64);
        hv[mt] += __shfl_xor(hv[mt], 16, 64);
        hv[mt] += __shfl_xor(hv[mt], 32, 64);
    }
    if (lg == 0){
        #pragma unroll
        for (int mt = 0; mt < 4; ++mt){
            sPm[wv * 64 + mt * 16 + lr] = hm[mt];
            sPv[wv * 64 + mt * 16 + lr] = hv[mt];
        }
    }
    __syncthreads();
    if (tid < 64){
        float B21 = b21s[0], B22 = b22s[0];
        float m_ = B21, v_ = B22;
        #pragma unroll
        for (int k = 0; k < 8; ++k){
            m_ += sPm[k * 64 + tid];
            v_ += sPv[k * 64 + tid];
        }
        int t = t0 + tid;
        float lw = logf(w[t]);
        pm[t] = m_ + lw;
        pv[t] = v_ + 2.f * lw;
    }
}

// ---- reduce: per-batch logsumexp + epilogue ----
__global__ void reduce_kernel(const float* __restrict__ pm, const float* __restrict__ pv,
                              const float* __restrict__ l, float* __restrict__ out){
    int b = blockIdx.x;
    int tid = threadIdx.x;
    const float* Pm = pm + (size_t)b * 2048;
    const float* Pv = pv + (size_t)b * 2048;

    float mm = -1e30f, mv = -1e30f;
    for (int i = tid; i < 2048; i += 256){
        mm = fmaxf(mm, Pm[i]);
        mv = fmaxf(mv, Pv[i]);
    }
    __shared__ float redm[4], redv[4];
    #pragma unroll
    for (int off = 32; off > 0; off >>= 1){
        mm = fmaxf(mm, __shfl_xor(mm, off, 64));
        mv = fmaxf(mv, __shfl_xor(mv, off, 64));
    }
    int wv = tid >> 6;
    if ((tid & 63) == 0){ redm[wv] = mm; redv[wv] = mv; }
    __syncthreads();
    mm = fmaxf(fmaxf(redm[0], redm[1]), fmaxf(redm[2], redm[3]));
    mv = fmaxf(fmaxf(redv[0], redv[1]), fmaxf(redv[2], redv[3]));

    float sm = 0.f, sv = 0.f;
    for (int i = tid; i < 2048; i += 256){
        sm += expf(Pm[i] - mm);
        sv += expf(Pv[i] - mv);
    }
    #pragma unroll
    for (int off = 32; off > 0; off >>= 1){
        sm += __shfl_xor(sm, off, 64);
        sv += __shfl_xor(sv, off, 64);
    }
    __shared__ float red2m[4], red2v[4];
    if ((tid & 63) == 0){ red2m[wv] = sm; red2v[wv] = sv; }
    __syncthreads();
    if (tid == 0){
        sm = red2m[0] + red2m[1] + red2m[2] + red2m[3];
        sv = red2v[0] + red2v[1] + red2v[2] + red2v[3];
        float lsem = mm + logf(sm);
        float lsev = mv + logf(sv);
        float ll = logf(l[b]);
        out[b]      = ll - lsem;
        out[64 + b] = ll - 3.f * lsem - lsev;
    }
}

extern "C" void kernel_launch(void* const* d_in, const int* in_sizes, int n_in,
                              void* d_out, int out_size, void* d_ws, size_t ws_size,
                              hipStream_t stream){
    const float* rho   = (const float*)d_in[0];
    const float* c     = (const float*)d_in[1];
    const float* w     = (const float*)d_in[2];
    const float* l     = (const float*)d_in[3];
    const int*   roads = (const int*)  d_in[4];
    const float* f2_W1 = (const float*)d_in[5];
    const float* f2_b1 = (const float*)d_in[6];
    const float* f2_W2 = (const float*)d_in[7];
    const float* f2_b2 = (const float*)d_in[8];
    const float* f_W1  = (const float*)d_in[9];
    const float* f_b1  = (const float*)d_in[10];
    const float* f_W21 = (const float*)d_in[11];
    const float* f_b21 = (const float*)d_in[12];
    const float* f_W22 = (const float*)d_in[13];
    const float* f_b22 = (const float*)d_in[14];

    unsigned char* ws = (unsigned char*)d_ws;
    unsigned short* W1T = (unsigned short*)(ws);                 // 65536 B
    unsigned short* W2T = (unsigned short*)(ws + 65536);         // 65536 B
    unsigned short* W3T = (unsigned short*)(ws + 131072);        // 262144 B
    float* pm = (float*)(ws + 393216);                           // 524288 B
    float* pv = (float*)(ws + 393216 + 524288);                  // 524288 B

    prep_weights<<<768, 256, 0, stream>>>(f2_W1, f2_W2, f_W1, W1T, W2T, W3T);
    main_kernel<<<2048, 512, 0, stream>>>(rho, c, w, roads,
                                          W1T, f2_b1, W2T, f2_b2, W3T, f_b1,
                                          f_W21, f_b21, f_W22, f_b22, pm, pv);
    reduce_kernel<<<64, 256, 0, stream>>>(pm, pv, l, (float*)d_out);
}